// Round 3
// baseline (61.886 us; speedup 1.0000x reference)
//
#include <hip/hip_runtime.h>

// Lucas-Kanade optical flow, fused single kernel, v3.
// No LDS, no barriers. Vertical box sum streamed in registers
// (add entering product row, subtract exiting row recomputed from global,
// both with 1-iteration prefetch distance). Horizontal 15-tap window done
// with wave shuffles (each thread owns 4 consecutive columns).
// Derivatives kept unscaled (8*fx, 8*fy, 4*ft); exact power-of-2 rescale
// folded into the final u,v (factor 2).

constexpr int IH  = 2048;
constexpr int IW  = 2048;
constexpr int RAD = 7;
constexpr int WIN = 15;
constexpr int NT  = 64;              // 1 wave per block
constexpr int SW  = 240;             // output columns per block (lanes 0..59)
constexpr int RB  = 8;               // output rows per block
constexpr int SCAN = RB + WIN - 1;   // 22 scan rows

__device__ __forceinline__ int clampi(int v, int lo, int hi) {
    return v < lo ? lo : (v > hi ? hi : v);
}

__device__ __forceinline__ void load_row5(const float* __restrict__ img, int row,
                                          int pcb, bool xedge, float v[5]) {
    const float* rp = img + (size_t)row * IW;
    if (!xedge) {
        const float4 q = *reinterpret_cast<const float4*>(rp + pcb);  // 16B aligned
        v[0] = q.x; v[1] = q.y; v[2] = q.z; v[3] = q.w;
        v[4] = rp[pcb + 4];
    } else {
        #pragma unroll
        for (int c = 0; c < 5; ++c) v[c] = rp[clampi(pcb + c, 0, IW - 1)];
    }
}

// A0 = prev row r, A1 = prev row r+1, B0 = next row r, B1 = next row r+1
template<bool ADD>
__device__ __forceinline__ void accum5(float V[5][4],
                                       const float A0[5], const float A1[5],
                                       const float B0[5], const float B1[5],
                                       bool xedge, int pcb) {
    float g[5], m[5], e[5];
    #pragma unroll
    for (int c = 0; c < 5; ++c) {
        const float da = A1[c] - A0[c];   // prev vertical diff
        const float db = B1[c] - B0[c];   // next vertical diff
        const float dc = B0[c] - A0[c];   // temporal diffs
        const float dd = B1[c] - A1[c];
        m[c] = da + db;                           // -> fy8
        e[c] = dc + dd;                           // -> ft4
        g[c] = (A0[c] + A1[c]) + (B0[c] + B1[c]); // -> fx8 via horiz diff
    }
    #pragma unroll
    for (int c = 0; c < 4; ++c) {
        float fx = g[c + 1] - g[c];    // 8*fx
        float fy = m[c] + m[c + 1];    // 8*fy
        float ft = e[c] + e[c + 1];    // 4*ft
        if (xedge) {
            const int pc = pcb + c;
            if (pc < 0 || pc >= IW) { fx = 0.f; fy = 0.f; ft = 0.f; }
        }
        if (ADD) {
            V[0][c] += fx * fx; V[1][c] += fx * fy; V[2][c] += fy * fy;
            V[3][c] += fx * ft; V[4][c] += fy * ft;
        } else {
            V[0][c] -= fx * fx; V[1][c] -= fx * fy; V[2][c] -= fy * fy;
            V[3][c] -= fx * ft; V[4][c] -= fy * ft;
        }
    }
}

__global__ __launch_bounds__(NT, 4)
void lk_kernel(const float* __restrict__ Pimg, const float* __restrict__ Nimg,
               float* __restrict__ out) {
    const int t   = threadIdx.x;
    const int c0  = blockIdx.x * SW;
    const int r0  = blockIdx.y * RB;
    const int ci0 = 4 * t;                  // first owned tracked column
    const int pcb = c0 - 8 + ci0;           // its global column
    const bool xedge = (c0 == 0) || (c0 - 8 + 4 * NT > IW);

    float V[5][4];
    #pragma unroll
    for (int p = 0; p < 5; ++p)
        #pragma unroll
        for (int c = 0; c < 4; ++c) V[p][c] = 0.f;

    // register row caches: i* entering rows, o* exiting rows, [0]=prev [1]=next
    float iA[2][5], iB[2][5], nN[2][5], oA[2][5], oB[2][5], oN[2][5];
    #pragma unroll
    for (int im = 0; im < 2; ++im)
        #pragma unroll
        for (int c = 0; c < 5; ++c) {
            iA[im][c] = 0.f; oA[im][c] = 0.f; oB[im][c] = 0.f; oN[im][c] = 0.f;
        }

    // prologue: iB <- row (r0-RAD), nN <- row (r0-RAD+1)
    {
        const int ra = clampi(r0 - RAD, 0, IH - 1);
        const int rb = clampi(r0 - RAD + 1, 0, IH - 1);
        load_row5(Pimg, ra, pcb, xedge, iB[0]);
        load_row5(Nimg, ra, pcb, xedge, iB[1]);
        load_row5(Pimg, rb, pcb, xedge, nN[0]);
        load_row5(Nimg, rb, pcb, xedge, nN[1]);
    }

    #pragma unroll
    for (int sr = 0; sr < SCAN; ++sr) {
        const int pr = r0 - RAD + sr;       // entering product row

        // shift entering cache: iA=row pr, iB=row pr+1; prefetch row pr+2
        #pragma unroll
        for (int im = 0; im < 2; ++im)
            #pragma unroll
            for (int c = 0; c < 5; ++c) { iA[im][c] = iB[im][c]; iB[im][c] = nN[im][c]; }
        {
            const int rr = clampi(pr + 2, 0, IH - 1);
            load_row5(Pimg, rr, pcb, xedge, nN[0]);
            load_row5(Nimg, rr, pcb, xedge, nN[1]);
        }

        // shift exiting cache: oA=row pr-15, oB=row pr-14; prefetch row pr-13
        #pragma unroll
        for (int im = 0; im < 2; ++im)
            #pragma unroll
            for (int c = 0; c < 5; ++c) { oA[im][c] = oB[im][c]; oB[im][c] = oN[im][c]; }
        if (sr >= WIN - 2) {
            const int rr = clampi(pr - (WIN - 2), 0, IH - 1);
            load_row5(Pimg, rr, pcb, xedge, oN[0]);
            load_row5(Nimg, rr, pcb, xedge, oN[1]);
        }

        // vertical running box sum
        if (pr >= 0 && pr < IH)
            accum5<true>(V, iA[0], iB[0], iA[1], iB[1], xedge, pcb);
        if (sr >= WIN && (pr - WIN) >= 0)
            accum5<false>(V, oA[0], oB[0], oA[1], oB[1], xedge, pcb);

        // horizontal window + solve + store
        if (sr >= WIN - 1) {
            float a[5][4];
            #pragma unroll
            for (int p = 0; p < 5; ++p) {
                const float v0 = V[p][0], v1 = V[p][1], v2 = V[p][2], v3 = V[p][3];
                const float P  = (v0 + v1) + (v2 + v3);
                const float S1 = __shfl(P,  t + 1);
                const float S2 = __shfl(P,  t + 2);
                const float S3 = __shfl(P,  t + 3);
                const float q0 = __shfl(v0, t + 4);
                const float q1 = __shfl(v1, t + 4);
                const float q2 = __shfl(v2, t + 4);
                a[p][0] = ((P - v0) + S1) + (S2 + S3);
                a[p][1] = a[p][0] - v1 + q0;
                a[p][2] = a[p][1] - v2 + q1;
                a[p][3] = a[p][2] - v3 + q2;
            }

            const int i = pr - RAD;             // output row, in [r0, r0+RB)
            const int x = c0 + ci0;
            if (ci0 < SW && x < IW) {
                float4 qu, qv;
                float* uo = &qu.x; float* vo = &qv.x;
                #pragma unroll
                for (int c = 0; c < 4; ++c) {
                    const float Axx = a[0][c], Axy = a[1][c], Ayy = a[2][c];
                    const float bx = a[3][c], by = a[4][c];
                    const float det = Axx * Ayy - Axy * Axy;
                    const float rd  = __builtin_amdgcn_rcpf(det) * 2.0f; // fold scale
                    const bool  ok  = (det != 0.f);
                    uo[c] = ok ? (Ayy * bx - Axy * by) * rd : 0.f;
                    vo[c] = ok ? (Axx * by - Axy * bx) * rd : 0.f;
                }
                *reinterpret_cast<float4*>(out + (size_t)i * IW + x) = qu;
                *reinterpret_cast<float4*>(out + (size_t)IH * IW + (size_t)i * IW + x) = qv;
            }
        }
    }
}

extern "C" void kernel_launch(void* const* d_in, const int* in_sizes, int n_in,
                              void* d_out, int out_size, void* d_ws, size_t ws_size,
                              hipStream_t stream) {
    (void)in_sizes; (void)n_in; (void)d_ws; (void)ws_size; (void)out_size;
    const float* prev = (const float*)d_in[0];
    const float* nxt  = (const float*)d_in[1];
    float* out        = (float*)d_out;
    dim3 grid((IW + SW - 1) / SW, IH / RB);   // 9 x 256 = 2304 blocks
    dim3 block(NT);
    hipLaunchKernelGGL(lk_kernel, grid, block, 0, stream, prev, nxt, out);
}

// Round 4
// 34.084 us; speedup vs baseline: 1.8157x; 1.8157x over previous
//
#include <hip/hip_runtime.h>

// Lucas-Kanade optical flow v4: latency-oriented.
// - RB=4 rows/block -> 4608 one-wave blocks (16 waves/CU resident at <=128 VGPR)
// - per-row SP/DT precompute, 5th column via wave shuffle (4 vector loads/step)
// - XCD-chunked band swizzle so vertical-halo re-reads hit the local L2
// Derivatives unscaled (8fx, 8fy, 4ft); exact power-of-2 rescale (x2) folded
// into the final u,v.

constexpr int IH  = 2048;
constexpr int IW  = 2048;
constexpr int RAD = 7;
constexpr int WIN = 15;
constexpr int NT  = 64;              // 1 wave per block
constexpr int SW  = 240;             // output columns per block (lanes 0..59 store)
constexpr int RB  = 4;               // output rows per block
constexpr int SCAN = RB + WIN - 1;   // 18 scan rows
constexpr int NSTRIP = 9;            // ceil(2048/240)
constexpr int NBAND  = IH / RB;      // 512
constexpr int CHUNK  = NBAND / 8;    // 64 bands per XCD per strip

__device__ __forceinline__ int clampi(int v, int lo, int hi) {
    return v < lo ? lo : (v > hi ? hi : v);
}

// Per-row derived terms: sp = prev+next, dt = next-prev (5 columns).
struct Row { float sp[5]; float dt[5]; };

template<bool EDGE>
__device__ __forceinline__ void load_row(const float* __restrict__ P,
                                         const float* __restrict__ N,
                                         int row, int pcb, int t, Row& R) {
    row = clampi(row, 0, IH - 1);
    const float* rp = P + (size_t)row * IW;
    const float* rn = N + (size_t)row * IW;
    if (!EDGE) {
        const float4 q = *reinterpret_cast<const float4*>(rp + pcb); // 16B aligned
        const float4 r = *reinterpret_cast<const float4*>(rn + pcb);
        R.sp[0] = q.x + r.x; R.dt[0] = r.x - q.x;
        R.sp[1] = q.y + r.y; R.dt[1] = r.y - q.y;
        R.sp[2] = q.z + r.z; R.dt[2] = r.z - q.z;
        R.sp[3] = q.w + r.w; R.dt[3] = r.w - q.w;
        // 5th column = neighbor lane's column 0. Lane 63 wraps -> garbage,
        // but it only feeds product col 247 which no stored output reads.
        R.sp[4] = __shfl(R.sp[0], t + 1);
        R.dt[4] = __shfl(R.dt[0], t + 1);
    } else {
        #pragma unroll
        for (int c = 0; c < 5; ++c) {
            const int g = clampi(pcb + c, 0, IW - 1);
            const float p = rp[g], n = rn[g];
            R.sp[c] = p + n; R.dt[c] = n - p;
        }
    }
}

// Accumulate (ADD) or remove (SUB) product row (pair R0=row r, R1=row r+1).
template<bool SUB, bool EDGE>
__device__ __forceinline__ void accum(float V[5][4], const Row& R0, const Row& R1,
                                      const bool cvalid[4]) {
    float g[5], m[5], e[5];
    #pragma unroll
    for (int c = 0; c < 5; ++c) {
        g[c] = R0.sp[c] + R1.sp[c];   // -> 8*fx via horizontal diff
        m[c] = R1.sp[c] - R0.sp[c];   // -> 8*fy
        e[c] = R0.dt[c] + R1.dt[c];   // -> 4*ft
    }
    #pragma unroll
    for (int c = 0; c < 4; ++c) {
        float fx = g[c + 1] - g[c];
        float fy = m[c] + m[c + 1];
        float ft = e[c] + e[c + 1];
        if (EDGE && !cvalid[c]) { fx = 0.f; fy = 0.f; ft = 0.f; }
        if (!SUB) {
            V[0][c] += fx * fx; V[1][c] += fx * fy; V[2][c] += fy * fy;
            V[3][c] += fx * ft; V[4][c] += fy * ft;
        } else {
            V[0][c] -= fx * fx; V[1][c] -= fx * fy; V[2][c] -= fy * fy;
            V[3][c] -= fx * ft; V[4][c] -= fy * ft;
        }
    }
}

template<bool EDGE>
__device__ __forceinline__ void lk_body(const float* __restrict__ P,
                                        const float* __restrict__ N,
                                        float* __restrict__ out,
                                        int c0, int r0, int t) {
    const int ci0 = 4 * t;
    const int pcb = c0 - 8 + ci0;
    bool cvalid[4];
    #pragma unroll
    for (int c = 0; c < 4; ++c)
        cvalid[c] = ((unsigned)(pcb + c) < (unsigned)IW);

    float V[5][4] = {};

    Row E0, E1, X0, X1, X2;
    load_row<EDGE>(P, N, r0 - 7, pcb, t, E0);
    load_row<EDGE>(P, N, r0 - 6, pcb, t, E1);

    #pragma unroll
    for (int sr = 0; sr < SCAN; ++sr) {
        const int pr = r0 - RAD + sr;     // entering product row

        // issue loads first (hide under this step's compute)
        Row nE;
        load_row<EDGE>(P, N, pr + 2, pcb, t, nE);
        Row nX;
        if (sr >= 12 && sr <= 15)          // exit rows r0-7 .. r0-4
            load_row<EDGE>(P, N, pr - 12, pcb, t, nX);

        if (pr >= 0 && pr < IH)            // wave-uniform
            accum<false, EDGE>(V, E0, E1, cvalid);
        if (sr >= WIN) {
            const int po = pr - WIN;       // exiting product row
            if (po >= 0)
                accum<true, EDGE>(V, X0, X1, cvalid);
        }

        // register-ring shifts (renamed by full unroll)
        E0 = E1; E1 = nE;
        if (sr >= 12) { X0 = X1; X1 = X2; if (sr <= 15) X2 = nX; }

        if (sr >= WIN - 1) {
            // horizontal 15-tap via shuffles, 4 outputs per thread
            float a[5][4];
            #pragma unroll
            for (int p = 0; p < 5; ++p) {
                const float v0 = V[p][0], v1 = V[p][1], v2 = V[p][2], v3 = V[p][3];
                const float Pg = (v0 + v1) + (v2 + v3);
                const float S1 = __shfl(Pg, t + 1);
                const float S2 = __shfl(Pg, t + 2);
                const float S3 = __shfl(Pg, t + 3);
                const float q0 = __shfl(v0, t + 4);
                const float q1 = __shfl(v1, t + 4);
                const float q2 = __shfl(v2, t + 4);
                a[p][0] = ((Pg - v0) + S1) + (S2 + S3);
                a[p][1] = a[p][0] - v1 + q0;
                a[p][2] = a[p][1] - v2 + q1;
                a[p][3] = a[p][2] - v3 + q2;
            }
            const int i = pr - RAD;        // output row in [r0, r0+RB)
            const int x = c0 + ci0;
            if (ci0 < SW && x < IW) {
                float4 qu, qv;
                float* uo = &qu.x; float* vo = &qv.x;
                #pragma unroll
                for (int c = 0; c < 4; ++c) {
                    const float Axx = a[0][c], Axy = a[1][c], Ayy = a[2][c];
                    const float bx = a[3][c], by = a[4][c];
                    const float det = Axx * Ayy - Axy * Axy;
                    const float rd  = __builtin_amdgcn_rcpf(det) * 2.0f;
                    const bool  ok  = (det != 0.f);
                    uo[c] = ok ? (Ayy * bx - Axy * by) * rd : 0.f;
                    vo[c] = ok ? (Axx * by - Axy * bx) * rd : 0.f;
                }
                *reinterpret_cast<float4*>(out + (size_t)i * IW + x) = qu;
                *reinterpret_cast<float4*>(out + (size_t)IH * IW + (size_t)i * IW + x) = qv;
            }
        }
    }
}

__global__ __launch_bounds__(NT, 4)
void lk_kernel(const float* __restrict__ Pimg, const float* __restrict__ Nimg,
               float* __restrict__ out) {
    // XCD-chunked swizzle: XCD (bid%8) owns 64 contiguous bands of one strip,
    // so vertical-halo re-reads across adjacent bands hit the local L2.
    const int bid   = blockIdx.x;
    const int xcd   = bid & 7;
    const int idx   = bid >> 3;              // 0..575
    const int strip = idx / CHUNK;           // 0..8
    const int pos   = idx % CHUNK;
    const int band  = xcd * CHUNK + pos;     // 0..511
    const int c0 = strip * SW;
    const int r0 = band * RB;
    const int t  = threadIdx.x;
    if (strip == 0 || strip == NSTRIP - 1)
        lk_body<true>(Pimg, Nimg, out, c0, r0, t);
    else
        lk_body<false>(Pimg, Nimg, out, c0, r0, t);
}

extern "C" void kernel_launch(void* const* d_in, const int* in_sizes, int n_in,
                              void* d_out, int out_size, void* d_ws, size_t ws_size,
                              hipStream_t stream) {
    (void)in_sizes; (void)n_in; (void)d_ws; (void)ws_size; (void)out_size;
    const float* prev = (const float*)d_in[0];
    const float* nxt  = (const float*)d_in[1];
    float* out        = (float*)d_out;
    dim3 grid(NSTRIP * NBAND);               // 4608 one-wave blocks
    dim3 block(NT);
    hipLaunchKernelGGL(lk_kernel, grid, block, 0, stream, prev, nxt, out);
}